// Round 17
// baseline (577.475 us; speedup 1.0000x reference)
//
#include <hip/hip_runtime.h>
#include <hip/hip_bf16.h>

#define EPS_BN 1e-5f

constexpr int B  = 2048, F0 = 64, K = 14;
constexpr int C1 = 64,  F1 = 32;
constexpr int C2 = 128, F2 = 16;
constexpr int C3 = 256, F3 = 8;

typedef __attribute__((ext_vector_type(8))) short bf16x8;
typedef __attribute__((ext_vector_type(4))) float f32x4;

__device__ __forceinline__ float bf2f(unsigned short u) {
    union { unsigned int i; float f; } x; x.i = ((unsigned int)u) << 16; return x.f;
}
__device__ __forceinline__ unsigned short f2bf(float f) {
    union { float f; unsigned int i; } x; x.f = f;
    unsigned int r = (x.i + 0x7fffu + ((x.i >> 16) & 1u)) >> 16;
    return (unsigned short)r;
}

// async global->LDS 16B copy. HW: LDS dest = wave-uniform base + lane*16.
// Callers must keep whole waves active with per-lane-consecutive dests.
__device__ __forceinline__ void gl_lds16(const void* g, void* l) {
    __builtin_amdgcn_global_load_lds(
        (const __attribute__((address_space(1))) unsigned int*)g,
        (__attribute__((address_space(3))) unsigned int*)l,
        16, 0, 0);
}

// ---- fold BN into conv1 weights; also zero the 16B pad-source block ----
__global__ void repack_w1(const float* __restrict__ w1, const float* __restrict__ g,
                          const float* __restrict__ bb, const float* __restrict__ m,
                          const float* __restrict__ v, float* __restrict__ w1f,
                          float* __restrict__ t1, float* __restrict__ zbuf) {
    int i = blockIdx.x * 256 + threadIdx.x;
    if (i < 4) zbuf[i] = 0.0f;
    if (i < C1) {
        float s = g[i] * rsqrtf(v[i] + EPS_BN);
        t1[i] = bb[i] - m[i] * s;
    }
    if (i < C1 * 2 * 9) {
        int c = i / 18;
        float s = g[c] * rsqrtf(v[c] + EPS_BN);
        w1f[i] = w1[i] * s;
    }
}

// ---- repack conv weights into MFMA B-fragment layout, bf16, BN-folded ----
// wp[((chunk*COUT + n)*32) + kk] = W[tap][ci][n]*s[n], chunk=tap*(CIN/32)+cc, ci=cc*32+kk
template<int CIN, int COUT>
__global__ void repack_mfma(const float* __restrict__ w, const float* __restrict__ g,
                            const float* __restrict__ bb, const float* __restrict__ m,
                            const float* __restrict__ v, unsigned short* __restrict__ wp,
                            float* __restrict__ t) {
    int idx = blockIdx.x * 256 + threadIdx.x;
    if (idx < COUT) {
        float s = g[idx] * rsqrtf(v[idx] + EPS_BN);
        t[idx] = bb[idx] - m[idx] * s;
    }
    if (idx < 9 * CIN * COUT) {
        constexpr int CCS = CIN / 32;
        int kk = idx & 31;
        int rest = idx >> 5;
        int n = rest & (COUT - 1);
        int chunk = rest / COUT;
        int tap = chunk / CCS;
        int cc  = chunk & (CCS - 1);
        int ci = cc * 32 + kk;
        float s = g[n] * rsqrtf(v[n] + EPS_BN);
        wp[idx] = f2bf(w[(n * CIN + ci) * 9 + tap] * s);
    }
}

// ---- conv1 v2 (round-15, VERBATIM): 4 ch/thread, float4 weights, ushort4 st ----
__global__ void conv1_kernel(const float* __restrict__ x, const float* __restrict__ sig,
                             const float* __restrict__ w1f, const float* __restrict__ t1,
                             unsigned short* __restrict__ h1) {
    __shared__ float xs[F0 * K], ssg[F0 * K], wsh2[18 * C1], bsh[C1];
    int b = blockIdx.x, t = threadIdx.x;
    for (int i = t; i < F0 * K / 4; i += 256) {
        float4 xv = ((const float4*)(x + (size_t)b * F0 * K))[i];
        ((float4*)xs)[i] = xv;
        float4 sv = ((const float4*)(sig + (size_t)b * F0 * K))[i];
        sv.x *= 10.0f; sv.y *= 10.0f; sv.z *= 10.0f; sv.w *= 10.0f;
        ((float4*)ssg)[i] = sv;
    }
    for (int i = t; i < C1 * 18; i += 256) {
        int c = i / 18, r = i % 18;
        wsh2[r * C1 + c] = w1f[i];
    }
    if (t < C1) bsh[t] = t1[t];
    __syncthreads();
    const int c4 = (t & 15) * 4;
    const int pg = t >> 4;
    const float4 bias = *(const float4*)&bsh[c4];
    for (int pos = pg; pos < F1 * K; pos += 16) {
        int f = pos / K, k = pos % K;
        float a0 = bias.x, a1 = bias.y, a2 = bias.z, a3 = bias.w;
        #pragma unroll
        for (int df = 0; df < 3; ++df) {
            int fi = 2 * f + df - 1;
            if (fi < 0 || fi >= F0) continue;
            #pragma unroll
            for (int dk = 0; dk < 3; ++dk) {
                int ki = k + dk - 1;
                if (ki < 0 || ki >= K) continue;
                float xv = xs[fi * K + ki];
                float sv = ssg[fi * K + ki];
                float4 wx = *(const float4*)&wsh2[(df * 3 + dk) * C1 + c4];
                float4 ws = *(const float4*)&wsh2[(9 + df * 3 + dk) * C1 + c4];
                a0 = fmaf(xv, wx.x, fmaf(sv, ws.x, a0));
                a1 = fmaf(xv, wx.y, fmaf(sv, ws.y, a1));
                a2 = fmaf(xv, wx.z, fmaf(sv, ws.z, a2));
                a3 = fmaf(xv, wx.w, fmaf(sv, ws.w, a3));
            }
        }
        ushort4 o;
        o.x = f2bf(fmaxf(a0, 0.f));
        o.y = f2bf(fmaxf(a1, 0.f));
        o.z = f2bf(fmaxf(a2, 0.f));
        o.w = f2bf(fmaxf(a3, 0.f));
        *(ushort4*)&h1[(((size_t)b * F1 + f) * K + k) * C1 + c4] = o;
    }
}

// ---- conv2 v3: barrier-free, LDS-free, A direct from global ----
// conv2's K-loop (NIT=18, 8 MFMA/it) is too short to amortize staging +
// vmcnt(0) drain + 2 barriers. A-rows are 128B and L2-hot: load the MFMA
// A-fragment per-lane straight from h1 (16B aligned); pad rows select the
// zeroed global block per-lane (plain loads, unlike gl_lds16). No LDS, no
// barriers; occupancy reg-bound only (~102 total regs -> 4 waves/SIMD).
// A-side L2 traffic 24.6->73.7 KB/block (+28% total) -- cheap vs the
// removed fixed overhead.
template<int CIN, int COUT, int FIN, int MINW>
__launch_bounds__(256, MINW)
__global__ void conv_mfma_direct(const unsigned short* __restrict__ hin,
                                 const unsigned short* __restrict__ wp,
                                 const float* __restrict__ tb,
                                 const unsigned short* __restrict__ zero16,
                                 unsigned short* __restrict__ hout) {
    constexpr int G = 4;
    constexpr int NT = COUT / 64;
    constexpr int CCS = CIN / 32;
    constexpr int NIT = 9 * CCS;

    const int b = blockIdx.y;
    const int f2base = blockIdx.x * G;
    const int t = threadIdx.x;
    const int lane = t & 63;
    const int wave = t >> 6;
    const int m = lane & 15;
    const int quad = lane >> 4;
    const int nBase = wave * (COUT / 4);

    f32x4 acc[G][NT];
    #pragma unroll
    for (int nt = 0; nt < NT; ++nt) {
        float bias = tb[nBase + nt * 16 + m];
        #pragma unroll
        for (int g = 0; g < G; ++g)
            acc[g][nt] = f32x4{bias, bias, bias, bias};
    }

    auto loadA = [&](int it, bf16x8* av) {
        int df = it / (3 * CCS), dk = (it / CCS) % 3, cc = it % CCS;
        int kin = m + dk - 1;                 // row in [-1, 16]
        bool krow = (kin >= 0) & (kin < K);
        #pragma unroll
        for (int g = 0; g < G; ++g) {
            int fi = 2 * (f2base + g) + df - 1;   // < FIN always; >=0 except g=0,df=0,f2base=0
            const unsigned short* src = (krow & (fi >= 0))
                ? hin + (((size_t)(b * FIN + fi)) * K + kin) * CIN + cc * 32 + quad * 8
                : zero16;
            av[g] = *(const bf16x8*)src;
        }
    };
    auto loadB = [&](int it, bf16x8* bv) {
        #pragma unroll
        for (int nt = 0; nt < NT; ++nt)
            bv[nt] = *(const bf16x8*)(wp + (((it * COUT + nBase + nt * 16 + m)) << 5) + quad * 8);
    };
    auto domfma = [&](bf16x8* av, bf16x8* bv) {
        #pragma unroll
        for (int g = 0; g < G; ++g)
            #pragma unroll
            for (int nt = 0; nt < NT; ++nt)
                acc[g][nt] = __builtin_amdgcn_mfma_f32_16x16x32_bf16(av[g], bv[nt], acc[g][nt], 0, 0, 0);
    };

    bf16x8 av[G], bA[NT], bB[NT];
    loadB(0, bA);
    #pragma unroll
    for (int it = 0; it < NIT; it += 2) {
        loadB(it + 1, bB);
        loadA(it, av);
        domfma(av, bA);
        if (it + 2 < NIT) loadB(it + 2, bA);
        loadA(it + 1, av);
        domfma(av, bB);
    }

    #pragma unroll
    for (int g = 0; g < G; ++g) {
        size_t rowbase = ((size_t)(b * (FIN / 2) + f2base + g)) * K;
        #pragma unroll
        for (int nt = 0; nt < NT; ++nt) {
            int col = nBase + nt * 16 + m;
            #pragma unroll
            for (int i = 0; i < 4; ++i) {
                int row = quad * 4 + i;
                if (row < K)
                    hout[(rowbase + row) * COUT + col] = f2bf(fmaxf(acc[g][nt][i], 0.f));
            }
        }
    }
}

// ---- conv3 + fused conv4 (round-11, VERBATIM — 169us, 84 VGPR, no spill) ----
template<int CIN, int COUT, int FIN, int MINW>
__launch_bounds__(256, MINW)
__global__ void conv_mfma_fused(const unsigned short* __restrict__ hin,
                                const unsigned short* __restrict__ wp,
                                const float* __restrict__ tb,
                                const unsigned short* __restrict__ zero16,
                                const float* __restrict__ w4,
                                float* __restrict__ pb) {
    constexpr int G = 4;
    constexpr int CHW = CIN / 8;
    constexpr int LOGC = (CHW == 16) ? 4 : 3;
    constexpr int NT = COUT / 64;
    constexpr int CCS = CIN / 32;
    constexpr int NIT = 9 * CCS;
    __shared__ alignas(16) unsigned short lin[G * 3 * 16 * CIN];
    __shared__ float red[4][4][4][2];        // [wave][quad][i][j]

    const int b = blockIdx.y;
    const int f2base = blockIdx.x * G;
    const int t = threadIdx.x;

    {
        constexpr int TOT = G * 3 * 16 * CHW;
        #pragma unroll
        for (int i = t; i < TOT; i += 256) {
            int c8 = i & (CHW - 1);
            int row = i >> LOGC;
            int p = row & 15;
            int tile = row >> 4;
            int df = tile % 3, g = tile / 3;
            int kin = p - 1;
            int fi = 2 * (f2base + g) + df - 1;
            bool valid = (kin >= 0) & (kin < K) & (fi >= 0);
            const unsigned short* src = valid
                ? hin + (((size_t)(b * FIN + fi)) * K + kin) * CIN + ((c8 ^ (p & 7)) << 3)
                : zero16;
            gl_lds16(src, &lin[i * 8]);
        }
    }
    __syncthreads();

    const int lane = t & 63;
    const int wave = t >> 6;
    const int m = lane & 15;
    const int quad = lane >> 4;
    const int nBase = wave * (COUT / 4);

    f32x4 acc[G][NT];
    #pragma unroll
    for (int nt = 0; nt < NT; ++nt) {
        float bias = tb[nBase + nt * 16 + m];
        #pragma unroll
        for (int g = 0; g < G; ++g)
            acc[g][nt] = f32x4{bias, bias, bias, bias};
    }

    auto loadA = [&](int it, bf16x8* av) {
        int df = it / (3 * CCS), dk = (it / CCS) % 3, cc = it % CCS;
        int p = m + dk; p = (p > 15) ? 15 : p;
        int cidx = (((cc * 4 + quad) ^ (p & 7)) << 3);
        #pragma unroll
        for (int g = 0; g < G; ++g)
            av[g] = *(const bf16x8*)&lin[((g * 3 + df) * 16 + p) * CIN + cidx];
    };
    auto loadB = [&](int it, bf16x8* bv) {
        int df = it / (3 * CCS), dk = (it / CCS) % 3, cc = it % CCS;
        int chunk = (df * 3 + dk) * CCS + cc;
        #pragma unroll
        for (int nt = 0; nt < NT; ++nt)
            bv[nt] = *(const bf16x8*)(wp + (((chunk * COUT + nBase + nt * 16 + m)) << 5) + quad * 8);
    };
    auto domfma = [&](bf16x8* av, bf16x8* bv) {
        #pragma unroll
        for (int g = 0; g < G; ++g)
            #pragma unroll
            for (int nt = 0; nt < NT; ++nt)
                acc[g][nt] = __builtin_amdgcn_mfma_f32_16x16x32_bf16(av[g], bv[nt], acc[g][nt], 0, 0, 0);
    };

    bf16x8 av[G], bA[NT], bB[NT];
    loadB(0, bA);
    #pragma unroll
    for (int it = 0; it < NIT; it += 2) {
        loadB(it + 1, bB);
        loadA(it, av);
        domfma(av, bA);
        if (it + 2 < NIT) loadB(it + 2, bA);
        loadA(it + 1, av);
        domfma(av, bB);
    }

    // ---- fused conv4 epilogue ----
    float part[4][2];
    #pragma unroll
    for (int i = 0; i < 4; ++i) { part[i][0] = 0.f; part[i][1] = 0.f; }
    #pragma unroll
    for (int g = 0; g < G; ++g) {
        int f = f2base + g;
        #pragma unroll
        for (int nt = 0; nt < NT; ++nt) {
            int c = nBase + nt * 16 + m;
            float w0 = w4[(0 * COUT + c) * F3 + f];
            float w1 = w4[(1 * COUT + c) * F3 + f];
            #pragma unroll
            for (int i = 0; i < 4; ++i) {
                float v = fmaxf(acc[g][nt][i], 0.f);
                part[i][0] = fmaf(v, w0, part[i][0]);
                part[i][1] = fmaf(v, w1, part[i][1]);
            }
        }
    }
    if (quad == 3) { part[2][0] = 0.f; part[2][1] = 0.f; part[3][0] = 0.f; part[3][1] = 0.f; }
    #pragma unroll
    for (int i = 0; i < 4; ++i)
        #pragma unroll
        for (int j = 0; j < 2; ++j) {
            float v = part[i][j];
            v += __shfl_xor(v, 1, 64);
            v += __shfl_xor(v, 2, 64);
            v += __shfl_xor(v, 4, 64);
            v += __shfl_xor(v, 8, 64);
            part[i][j] = v;
        }
    if (m == 0) {
        #pragma unroll
        for (int i = 0; i < 4; ++i) {
            red[wave][quad][i][0] = part[i][0];
            red[wave][quad][i][1] = part[i][1];
        }
    }
    __syncthreads();
    if (t < 2 * K) {
        int k = t >> 1, j = t & 1;
        float s = red[0][k >> 2][k & 3][j] + red[1][k >> 2][k & 3][j]
                + red[2][k >> 2][k & 3][j] + red[3][k >> 2][k & 3][j];
        pb[((size_t)b * 2 + blockIdx.x) * (2 * K) + t] = s;
    }
}

// ---- final: out[b,k,j] = pb[b][0][...] + pb[b][1][...] ----
__global__ void fin_kernel(const float* __restrict__ pb, float* __restrict__ out) {
    int idx = blockIdx.x * 256 + threadIdx.x;
    if (idx < B * 2 * K) {
        int b = idx / (2 * K), r = idx % (2 * K);
        out[idx] = pb[(size_t)b * (4 * K) + r] + pb[(size_t)b * (4 * K) + 2 * K + r];
    }
}

extern "C" void kernel_launch(void* const* d_in, const int* in_sizes, int n_in,
                              void* d_out, int out_size, void* d_ws, size_t ws_size,
                              hipStream_t stream) {
    const float* x   = (const float*)d_in[0];
    const float* sig = (const float*)d_in[1];
    const float* w1  = (const float*)d_in[2];
    const float* w2  = (const float*)d_in[3];
    const float* w3  = (const float*)d_in[4];
    const float* w4  = (const float*)d_in[5];
    const float* g1  = (const float*)d_in[6];
    const float* b1  = (const float*)d_in[7];
    const float* m1  = (const float*)d_in[8];
    const float* v1  = (const float*)d_in[9];
    const float* g2  = (const float*)d_in[10];
    const float* b2  = (const float*)d_in[11];
    const float* m2  = (const float*)d_in[12];
    const float* v2  = (const float*)d_in[13];
    const float* g3  = (const float*)d_in[14];
    const float* b3  = (const float*)d_in[15];
    const float* m3  = (const float*)d_in[16];
    const float* v3  = (const float*)d_in[17];

    char* ws = (char*)d_ws;
    size_t off = 0;
    auto alloc = [&](size_t bytes) {
        char* p = ws + off;
        off += (bytes + 255) & ~(size_t)255;
        return p;
    };
    unsigned short* h1  = (unsigned short*)alloc((size_t)B * F1 * K * C1 * 2);
    unsigned short* h2  = (unsigned short*)alloc((size_t)B * F2 * K * C2 * 2);
    float* w1f = (float*)alloc((size_t)C1 * 2 * 9 * 4);
    float* t1  = (float*)alloc((size_t)C1 * 4);
    unsigned short* wp2 = (unsigned short*)alloc((size_t)9 * C1 * C2 * 2);
    float* t2  = (float*)alloc((size_t)C2 * 4);
    unsigned short* wp3 = (unsigned short*)alloc((size_t)9 * C2 * C3 * 2);
    float* t3  = (float*)alloc((size_t)C3 * 4);
    float* zbuf = (float*)alloc(16);
    float* pb   = (float*)alloc((size_t)B * 2 * 2 * K * 4);   // per-block conv4 partials

    repack_w1<<<(C1 * 2 * 9 + 255) / 256, 256, 0, stream>>>(w1, g1, b1, m1, v1, w1f, t1, zbuf);
    repack_mfma<C1, C2><<<(9 * C1 * C2 + 255) / 256, 256, 0, stream>>>(w2, g2, b2, m2, v2, wp2, t2);
    repack_mfma<C2, C3><<<(9 * C2 * C3 + 255) / 256, 256, 0, stream>>>(w3, g3, b3, m3, v3, wp3, t3);

    conv1_kernel<<<B, 256, 0, stream>>>(x, sig, w1f, t1, h1);
    // conv2: barrier-free direct-A -> grid (4, B); LDS 0; MINW=4
    conv_mfma_direct<C1, C2, F1, 4><<<dim3(F1 / 2 / 4, B), 256, 0, stream>>>(h1, wp2, t2, (const unsigned short*)zbuf, h2);
    // conv3 + fused conv4: grid (2, B); writes 28-float partials per block
    conv_mfma_fused<C2, C3, F2, 3><<<dim3(F2 / 2 / 4, B), 256, 0, stream>>>(h2, wp3, t3, (const unsigned short*)zbuf, w4, pb);
    fin_kernel<<<(B * 2 * K + 255) / 256, 256, 0, stream>>>(pb, (float*)d_out);
}

// Round 18
// 394.754 us; speedup vs baseline: 1.4629x; 1.4629x over previous
//
#include <hip/hip_runtime.h>
#include <hip/hip_bf16.h>

#define EPS_BN 1e-5f

constexpr int B  = 2048, F0 = 64, K = 14;
constexpr int C1 = 64,  F1 = 32;
constexpr int C2 = 128, F2 = 16;
constexpr int C3 = 256, F3 = 8;

typedef __attribute__((ext_vector_type(8))) short bf16x8;
typedef __attribute__((ext_vector_type(4))) float f32x4;

__device__ __forceinline__ float bf2f(unsigned short u) {
    union { unsigned int i; float f; } x; x.i = ((unsigned int)u) << 16; return x.f;
}
__device__ __forceinline__ unsigned short f2bf(float f) {
    union { float f; unsigned int i; } x; x.f = f;
    unsigned int r = (x.i + 0x7fffu + ((x.i >> 16) & 1u)) >> 16;
    return (unsigned short)r;
}

// async global->LDS 16B copy. HW: LDS dest = wave-uniform base + lane*16.
// Callers must keep whole waves active with per-lane-consecutive dests.
__device__ __forceinline__ void gl_lds16(const void* g, void* l) {
    __builtin_amdgcn_global_load_lds(
        (const __attribute__((address_space(1))) unsigned int*)g,
        (__attribute__((address_space(3))) unsigned int*)l,
        16, 0, 0);
}

// ---- fold BN into conv1 weights; also zero the 16B pad-source block ----
__global__ void repack_w1(const float* __restrict__ w1, const float* __restrict__ g,
                          const float* __restrict__ bb, const float* __restrict__ m,
                          const float* __restrict__ v, float* __restrict__ w1f,
                          float* __restrict__ t1, float* __restrict__ zbuf) {
    int i = blockIdx.x * 256 + threadIdx.x;
    if (i < 4) zbuf[i] = 0.0f;
    if (i < C1) {
        float s = g[i] * rsqrtf(v[i] + EPS_BN);
        t1[i] = bb[i] - m[i] * s;
    }
    if (i < C1 * 2 * 9) {
        int c = i / 18;
        float s = g[c] * rsqrtf(v[c] + EPS_BN);
        w1f[i] = w1[i] * s;
    }
}

// ---- repack conv weights into MFMA B-fragment layout, bf16, BN-folded ----
// wp[((chunk*COUT + n)*32) + kk] = W[tap][ci][n]*s[n], chunk=tap*(CIN/32)+cc, ci=cc*32+kk
template<int CIN, int COUT>
__global__ void repack_mfma(const float* __restrict__ w, const float* __restrict__ g,
                            const float* __restrict__ bb, const float* __restrict__ m,
                            const float* __restrict__ v, unsigned short* __restrict__ wp,
                            float* __restrict__ t) {
    int idx = blockIdx.x * 256 + threadIdx.x;
    if (idx < COUT) {
        float s = g[idx] * rsqrtf(v[idx] + EPS_BN);
        t[idx] = bb[idx] - m[idx] * s;
    }
    if (idx < 9 * CIN * COUT) {
        constexpr int CCS = CIN / 32;
        int kk = idx & 31;
        int rest = idx >> 5;
        int n = rest & (COUT - 1);
        int chunk = rest / COUT;
        int tap = chunk / CCS;
        int cc  = chunk & (CCS - 1);
        int ci = cc * 32 + kk;
        float s = g[n] * rsqrtf(v[n] + EPS_BN);
        wp[idx] = f2bf(w[(n * CIN + ci) * 9 + tap] * s);
    }
}

// ---- conv1 v2 (round-15, VERBATIM): 4 ch/thread, float4 weights, ushort4 st ----
__global__ void conv1_kernel(const float* __restrict__ x, const float* __restrict__ sig,
                             const float* __restrict__ w1f, const float* __restrict__ t1,
                             unsigned short* __restrict__ h1) {
    __shared__ float xs[F0 * K], ssg[F0 * K], wsh2[18 * C1], bsh[C1];
    int b = blockIdx.x, t = threadIdx.x;
    for (int i = t; i < F0 * K / 4; i += 256) {
        float4 xv = ((const float4*)(x + (size_t)b * F0 * K))[i];
        ((float4*)xs)[i] = xv;
        float4 sv = ((const float4*)(sig + (size_t)b * F0 * K))[i];
        sv.x *= 10.0f; sv.y *= 10.0f; sv.z *= 10.0f; sv.w *= 10.0f;
        ((float4*)ssg)[i] = sv;
    }
    for (int i = t; i < C1 * 18; i += 256) {
        int c = i / 18, r = i % 18;
        wsh2[r * C1 + c] = w1f[i];
    }
    if (t < C1) bsh[t] = t1[t];
    __syncthreads();
    const int c4 = (t & 15) * 4;
    const int pg = t >> 4;
    const float4 bias = *(const float4*)&bsh[c4];
    for (int pos = pg; pos < F1 * K; pos += 16) {
        int f = pos / K, k = pos % K;
        float a0 = bias.x, a1 = bias.y, a2 = bias.z, a3 = bias.w;
        #pragma unroll
        for (int df = 0; df < 3; ++df) {
            int fi = 2 * f + df - 1;
            if (fi < 0 || fi >= F0) continue;
            #pragma unroll
            for (int dk = 0; dk < 3; ++dk) {
                int ki = k + dk - 1;
                if (ki < 0 || ki >= K) continue;
                float xv = xs[fi * K + ki];
                float sv = ssg[fi * K + ki];
                float4 wx = *(const float4*)&wsh2[(df * 3 + dk) * C1 + c4];
                float4 ws = *(const float4*)&wsh2[(9 + df * 3 + dk) * C1 + c4];
                a0 = fmaf(xv, wx.x, fmaf(sv, ws.x, a0));
                a1 = fmaf(xv, wx.y, fmaf(sv, ws.y, a1));
                a2 = fmaf(xv, wx.z, fmaf(sv, ws.z, a2));
                a3 = fmaf(xv, wx.w, fmaf(sv, ws.w, a3));
            }
        }
        ushort4 o;
        o.x = f2bf(fmaxf(a0, 0.f));
        o.y = f2bf(fmaxf(a1, 0.f));
        o.z = f2bf(fmaxf(a2, 0.f));
        o.w = f2bf(fmaxf(a3, 0.f));
        *(ushort4*)&h1[(((size_t)b * F1 + f) * K + k) * C1 + c4] = o;
    }
}

// ---- conv2 as MFMA GEMM: round-2 structure VERBATIM (proven, part of the
// 395.7us config). G=4 per-(g,df) LDS tiles, flat it-loop, 2-deep bv rot.
// Direct-A (r17) regressed 2x: staged LDS gives coalesced DMA + 4-wave
// A-reuse that per-lane global loads lack.
template<int CIN, int COUT, int FIN, int MINW>
__launch_bounds__(256, MINW)
__global__ void conv_mfma(const unsigned short* __restrict__ hin,
                          const unsigned short* __restrict__ wp,
                          const float* __restrict__ tb,
                          const unsigned short* __restrict__ zero16,
                          unsigned short* __restrict__ hout) {
    constexpr int G = 4;
    constexpr int CHW = CIN / 8;
    constexpr int LOGC = (CHW == 16) ? 4 : 3;
    constexpr int NT = COUT / 64;
    constexpr int CCS = CIN / 32;
    constexpr int NIT = 9 * CCS;
    __shared__ alignas(16) unsigned short lin[G * 3 * 16 * CIN];

    const int b = blockIdx.y;
    const int f2base = blockIdx.x * G;
    const int t = threadIdx.x;

    {
        constexpr int TOT = G * 3 * 16 * CHW;
        #pragma unroll
        for (int i = t; i < TOT; i += 256) {
            int c8 = i & (CHW - 1);
            int row = i >> LOGC;
            int p = row & 15;
            int tile = row >> 4;
            int df = tile % 3, g = tile / 3;
            int kin = p - 1;
            int fi = 2 * (f2base + g) + df - 1;
            bool valid = (kin >= 0) & (kin < K) & (fi >= 0);
            const unsigned short* src = valid
                ? hin + (((size_t)(b * FIN + fi)) * K + kin) * CIN + ((c8 ^ (p & 7)) << 3)
                : zero16;
            gl_lds16(src, &lin[i * 8]);
        }
    }
    __syncthreads();

    const int lane = t & 63;
    const int wave = t >> 6;
    const int m = lane & 15;
    const int quad = lane >> 4;
    const int nBase = wave * (COUT / 4);

    f32x4 acc[G][NT];
    #pragma unroll
    for (int nt = 0; nt < NT; ++nt) {
        float bias = tb[nBase + nt * 16 + m];
        #pragma unroll
        for (int g = 0; g < G; ++g)
            acc[g][nt] = f32x4{bias, bias, bias, bias};
    }

    auto loadA = [&](int it, bf16x8* av) {
        int df = it / (3 * CCS), dk = (it / CCS) % 3, cc = it % CCS;
        int p = m + dk; p = (p > 15) ? 15 : p;
        int cidx = (((cc * 4 + quad) ^ (p & 7)) << 3);
        #pragma unroll
        for (int g = 0; g < G; ++g)
            av[g] = *(const bf16x8*)&lin[((g * 3 + df) * 16 + p) * CIN + cidx];
    };
    auto loadB = [&](int it, bf16x8* bv) {
        int df = it / (3 * CCS), dk = (it / CCS) % 3, cc = it % CCS;
        int chunk = (df * 3 + dk) * CCS + cc;
        #pragma unroll
        for (int nt = 0; nt < NT; ++nt)
            bv[nt] = *(const bf16x8*)(wp + (((chunk * COUT + nBase + nt * 16 + m)) << 5) + quad * 8);
    };
    auto domfma = [&](bf16x8* av, bf16x8* bv) {
        #pragma unroll
        for (int g = 0; g < G; ++g)
            #pragma unroll
            for (int nt = 0; nt < NT; ++nt)
                acc[g][nt] = __builtin_amdgcn_mfma_f32_16x16x32_bf16(av[g], bv[nt], acc[g][nt], 0, 0, 0);
    };

    bf16x8 av[G], bA[NT], bB[NT];
    loadB(0, bA);
    #pragma unroll
    for (int it = 0; it < NIT; it += 2) {
        loadB(it + 1, bB);
        loadA(it, av);
        domfma(av, bA);
        if (it + 2 < NIT) loadB(it + 2, bA);
        loadA(it + 1, av);
        domfma(av, bB);
    }

    #pragma unroll
    for (int g = 0; g < G; ++g) {
        size_t rowbase = ((size_t)(b * (FIN / 2) + f2base + g)) * K;
        #pragma unroll
        for (int nt = 0; nt < NT; ++nt) {
            int col = nBase + nt * 16 + m;
            #pragma unroll
            for (int i = 0; i < 4; ++i) {
                int row = quad * 4 + i;
                if (row < K)
                    hout[(rowbase + row) * COUT + col] = f2bf(fmaxf(acc[g][nt][i], 0.f));
            }
        }
    }
}

// ---- conv3 + fused conv4 (round-11, VERBATIM — 169us, 84 VGPR, no spill) ----
template<int CIN, int COUT, int FIN, int MINW>
__launch_bounds__(256, MINW)
__global__ void conv_mfma_fused(const unsigned short* __restrict__ hin,
                                const unsigned short* __restrict__ wp,
                                const float* __restrict__ tb,
                                const unsigned short* __restrict__ zero16,
                                const float* __restrict__ w4,
                                float* __restrict__ pb) {
    constexpr int G = 4;
    constexpr int CHW = CIN / 8;
    constexpr int LOGC = (CHW == 16) ? 4 : 3;
    constexpr int NT = COUT / 64;
    constexpr int CCS = CIN / 32;
    constexpr int NIT = 9 * CCS;
    __shared__ alignas(16) unsigned short lin[G * 3 * 16 * CIN];
    __shared__ float red[4][4][4][2];        // [wave][quad][i][j]

    const int b = blockIdx.y;
    const int f2base = blockIdx.x * G;
    const int t = threadIdx.x;

    {
        constexpr int TOT = G * 3 * 16 * CHW;
        #pragma unroll
        for (int i = t; i < TOT; i += 256) {
            int c8 = i & (CHW - 1);
            int row = i >> LOGC;
            int p = row & 15;
            int tile = row >> 4;
            int df = tile % 3, g = tile / 3;
            int kin = p - 1;
            int fi = 2 * (f2base + g) + df - 1;
            bool valid = (kin >= 0) & (kin < K) & (fi >= 0);
            const unsigned short* src = valid
                ? hin + (((size_t)(b * FIN + fi)) * K + kin) * CIN + ((c8 ^ (p & 7)) << 3)
                : zero16;
            gl_lds16(src, &lin[i * 8]);
        }
    }
    __syncthreads();

    const int lane = t & 63;
    const int wave = t >> 6;
    const int m = lane & 15;
    const int quad = lane >> 4;
    const int nBase = wave * (COUT / 4);

    f32x4 acc[G][NT];
    #pragma unroll
    for (int nt = 0; nt < NT; ++nt) {
        float bias = tb[nBase + nt * 16 + m];
        #pragma unroll
        for (int g = 0; g < G; ++g)
            acc[g][nt] = f32x4{bias, bias, bias, bias};
    }

    auto loadA = [&](int it, bf16x8* av) {
        int df = it / (3 * CCS), dk = (it / CCS) % 3, cc = it % CCS;
        int p = m + dk; p = (p > 15) ? 15 : p;
        int cidx = (((cc * 4 + quad) ^ (p & 7)) << 3);
        #pragma unroll
        for (int g = 0; g < G; ++g)
            av[g] = *(const bf16x8*)&lin[((g * 3 + df) * 16 + p) * CIN + cidx];
    };
    auto loadB = [&](int it, bf16x8* bv) {
        int df = it / (3 * CCS), dk = (it / CCS) % 3, cc = it % CCS;
        int chunk = (df * 3 + dk) * CCS + cc;
        #pragma unroll
        for (int nt = 0; nt < NT; ++nt)
            bv[nt] = *(const bf16x8*)(wp + (((chunk * COUT + nBase + nt * 16 + m)) << 5) + quad * 8);
    };
    auto domfma = [&](bf16x8* av, bf16x8* bv) {
        #pragma unroll
        for (int g = 0; g < G; ++g)
            #pragma unroll
            for (int nt = 0; nt < NT; ++nt)
                acc[g][nt] = __builtin_amdgcn_mfma_f32_16x16x32_bf16(av[g], bv[nt], acc[g][nt], 0, 0, 0);
    };

    bf16x8 av[G], bA[NT], bB[NT];
    loadB(0, bA);
    #pragma unroll
    for (int it = 0; it < NIT; it += 2) {
        loadB(it + 1, bB);
        loadA(it, av);
        domfma(av, bA);
        if (it + 2 < NIT) loadB(it + 2, bA);
        loadA(it + 1, av);
        domfma(av, bB);
    }

    // ---- fused conv4 epilogue ----
    float part[4][2];
    #pragma unroll
    for (int i = 0; i < 4; ++i) { part[i][0] = 0.f; part[i][1] = 0.f; }
    #pragma unroll
    for (int g = 0; g < G; ++g) {
        int f = f2base + g;
        #pragma unroll
        for (int nt = 0; nt < NT; ++nt) {
            int c = nBase + nt * 16 + m;
            float w0 = w4[(0 * COUT + c) * F3 + f];
            float w1 = w4[(1 * COUT + c) * F3 + f];
            #pragma unroll
            for (int i = 0; i < 4; ++i) {
                float v = fmaxf(acc[g][nt][i], 0.f);
                part[i][0] = fmaf(v, w0, part[i][0]);
                part[i][1] = fmaf(v, w1, part[i][1]);
            }
        }
    }
    if (quad == 3) { part[2][0] = 0.f; part[2][1] = 0.f; part[3][0] = 0.f; part[3][1] = 0.f; }
    #pragma unroll
    for (int i = 0; i < 4; ++i)
        #pragma unroll
        for (int j = 0; j < 2; ++j) {
            float v = part[i][j];
            v += __shfl_xor(v, 1, 64);
            v += __shfl_xor(v, 2, 64);
            v += __shfl_xor(v, 4, 64);
            v += __shfl_xor(v, 8, 64);
            part[i][j] = v;
        }
    if (m == 0) {
        #pragma unroll
        for (int i = 0; i < 4; ++i) {
            red[wave][quad][i][0] = part[i][0];
            red[wave][quad][i][1] = part[i][1];
        }
    }
    __syncthreads();
    if (t < 2 * K) {
        int k = t >> 1, j = t & 1;
        float s = red[0][k >> 2][k & 3][j] + red[1][k >> 2][k & 3][j]
                + red[2][k >> 2][k & 3][j] + red[3][k >> 2][k & 3][j];
        pb[((size_t)b * 2 + blockIdx.x) * (2 * K) + t] = s;
    }
}

// ---- final: out[b,k,j] = pb[b][0][...] + pb[b][1][...] ----
__global__ void fin_kernel(const float* __restrict__ pb, float* __restrict__ out) {
    int idx = blockIdx.x * 256 + threadIdx.x;
    if (idx < B * 2 * K) {
        int b = idx / (2 * K), r = idx % (2 * K);
        out[idx] = pb[(size_t)b * (4 * K) + r] + pb[(size_t)b * (4 * K) + 2 * K + r];
    }
}

extern "C" void kernel_launch(void* const* d_in, const int* in_sizes, int n_in,
                              void* d_out, int out_size, void* d_ws, size_t ws_size,
                              hipStream_t stream) {
    const float* x   = (const float*)d_in[0];
    const float* sig = (const float*)d_in[1];
    const float* w1  = (const float*)d_in[2];
    const float* w2  = (const float*)d_in[3];
    const float* w3  = (const float*)d_in[4];
    const float* w4  = (const float*)d_in[5];
    const float* g1  = (const float*)d_in[6];
    const float* b1  = (const float*)d_in[7];
    const float* m1  = (const float*)d_in[8];
    const float* v1  = (const float*)d_in[9];
    const float* g2  = (const float*)d_in[10];
    const float* b2  = (const float*)d_in[11];
    const float* m2  = (const float*)d_in[12];
    const float* v2  = (const float*)d_in[13];
    const float* g3  = (const float*)d_in[14];
    const float* b3  = (const float*)d_in[15];
    const float* m3  = (const float*)d_in[16];
    const float* v3  = (const float*)d_in[17];

    char* ws = (char*)d_ws;
    size_t off = 0;
    auto alloc = [&](size_t bytes) {
        char* p = ws + off;
        off += (bytes + 255) & ~(size_t)255;
        return p;
    };
    unsigned short* h1  = (unsigned short*)alloc((size_t)B * F1 * K * C1 * 2);
    unsigned short* h2  = (unsigned short*)alloc((size_t)B * F2 * K * C2 * 2);
    float* w1f = (float*)alloc((size_t)C1 * 2 * 9 * 4);
    float* t1  = (float*)alloc((size_t)C1 * 4);
    unsigned short* wp2 = (unsigned short*)alloc((size_t)9 * C1 * C2 * 2);
    float* t2  = (float*)alloc((size_t)C2 * 4);
    unsigned short* wp3 = (unsigned short*)alloc((size_t)9 * C2 * C3 * 2);
    float* t3  = (float*)alloc((size_t)C3 * 4);
    float* zbuf = (float*)alloc(16);
    float* pb   = (float*)alloc((size_t)B * 2 * 2 * K * 4);   // per-block conv4 partials

    repack_w1<<<(C1 * 2 * 9 + 255) / 256, 256, 0, stream>>>(w1, g1, b1, m1, v1, w1f, t1, zbuf);
    repack_mfma<C1, C2><<<(9 * C1 * C2 + 255) / 256, 256, 0, stream>>>(w2, g2, b2, m2, v2, wp2, t2);
    repack_mfma<C2, C3><<<(9 * C2 * C3 + 255) / 256, 256, 0, stream>>>(w3, g3, b3, m3, v3, wp3, t3);

    conv1_kernel<<<B, 256, 0, stream>>>(x, sig, w1f, t1, h1);
    // conv2: round-2 structure, G=4 -> grid (4, B)
    conv_mfma<C1, C2, F1, 4><<<dim3(F1 / 2 / 4, B), 256, 0, stream>>>(h1, wp2, t2, (const unsigned short*)zbuf, h2);
    // conv3 + fused conv4: grid (2, B); writes 28-float partials per block
    conv_mfma_fused<C2, C3, F2, 3><<<dim3(F2 / 2 / 4, B), 256, 0, stream>>>(h2, wp3, t3, (const unsigned short*)zbuf, w4, pb);
    fin_kernel<<<(B * 2 * K + 255) / 256, 256, 0, stream>>>(pb, (float*)d_out);
}

// Round 19
// 378.953 us; speedup vs baseline: 1.5239x; 1.0417x over previous
//
#include <hip/hip_runtime.h>
#include <hip/hip_bf16.h>

#define EPS_BN 1e-5f

constexpr int B  = 2048, F0 = 64, K = 14;
constexpr int C1 = 64,  F1 = 32;
constexpr int C2 = 128, F2 = 16;
constexpr int C3 = 256, F3 = 8;

typedef __attribute__((ext_vector_type(8))) short bf16x8;
typedef __attribute__((ext_vector_type(4))) float f32x4;

__device__ __forceinline__ float bf2f(unsigned short u) {
    union { unsigned int i; float f; } x; x.i = ((unsigned int)u) << 16; return x.f;
}
__device__ __forceinline__ unsigned short f2bf(float f) {
    union { float f; unsigned int i; } x; x.f = f;
    unsigned int r = (x.i + 0x7fffu + ((x.i >> 16) & 1u)) >> 16;
    return (unsigned short)r;
}

// async global->LDS 16B copy. HW: LDS dest = wave-uniform base + lane*16.
// Callers must keep whole waves active with per-lane-consecutive dests.
__device__ __forceinline__ void gl_lds16(const void* g, void* l) {
    __builtin_amdgcn_global_load_lds(
        (const __attribute__((address_space(1))) unsigned int*)g,
        (__attribute__((address_space(3))) unsigned int*)l,
        16, 0, 0);
}

// ---- fold BN into conv1 weights; also zero the 16B pad-source block ----
__global__ void repack_w1(const float* __restrict__ w1, const float* __restrict__ g,
                          const float* __restrict__ bb, const float* __restrict__ m,
                          const float* __restrict__ v, float* __restrict__ w1f,
                          float* __restrict__ t1, float* __restrict__ zbuf) {
    int i = blockIdx.x * 256 + threadIdx.x;
    if (i < 4) zbuf[i] = 0.0f;
    if (i < C1) {
        float s = g[i] * rsqrtf(v[i] + EPS_BN);
        t1[i] = bb[i] - m[i] * s;
    }
    if (i < C1 * 2 * 9) {
        int c = i / 18;
        float s = g[c] * rsqrtf(v[c] + EPS_BN);
        w1f[i] = w1[i] * s;
    }
}

// ---- repack conv weights into MFMA B-fragment layout, bf16, BN-folded ----
// wp[((chunk*COUT + n)*32) + kk] = W[tap][ci][n]*s[n], chunk=tap*(CIN/32)+cc, ci=cc*32+kk
template<int CIN, int COUT>
__global__ void repack_mfma(const float* __restrict__ w, const float* __restrict__ g,
                            const float* __restrict__ bb, const float* __restrict__ m,
                            const float* __restrict__ v, unsigned short* __restrict__ wp,
                            float* __restrict__ t) {
    int idx = blockIdx.x * 256 + threadIdx.x;
    if (idx < COUT) {
        float s = g[idx] * rsqrtf(v[idx] + EPS_BN);
        t[idx] = bb[idx] - m[idx] * s;
    }
    if (idx < 9 * CIN * COUT) {
        constexpr int CCS = CIN / 32;
        int kk = idx & 31;
        int rest = idx >> 5;
        int n = rest & (COUT - 1);
        int chunk = rest / COUT;
        int tap = chunk / CCS;
        int cc  = chunk & (CCS - 1);
        int ci = cc * 32 + kk;
        float s = g[n] * rsqrtf(v[n] + EPS_BN);
        wp[idx] = f2bf(w[(n * CIN + ci) * 9 + tap] * s);
    }
}

// ---- conv1 v2 (round-15, VERBATIM): 4 ch/thread, float4 weights, ushort4 st ----
__global__ void conv1_kernel(const float* __restrict__ x, const float* __restrict__ sig,
                             const float* __restrict__ w1f, const float* __restrict__ t1,
                             unsigned short* __restrict__ h1) {
    __shared__ float xs[F0 * K], ssg[F0 * K], wsh2[18 * C1], bsh[C1];
    int b = blockIdx.x, t = threadIdx.x;
    for (int i = t; i < F0 * K / 4; i += 256) {
        float4 xv = ((const float4*)(x + (size_t)b * F0 * K))[i];
        ((float4*)xs)[i] = xv;
        float4 sv = ((const float4*)(sig + (size_t)b * F0 * K))[i];
        sv.x *= 10.0f; sv.y *= 10.0f; sv.z *= 10.0f; sv.w *= 10.0f;
        ((float4*)ssg)[i] = sv;
    }
    for (int i = t; i < C1 * 18; i += 256) {
        int c = i / 18, r = i % 18;
        wsh2[r * C1 + c] = w1f[i];
    }
    if (t < C1) bsh[t] = t1[t];
    __syncthreads();
    const int c4 = (t & 15) * 4;
    const int pg = t >> 4;
    const float4 bias = *(const float4*)&bsh[c4];
    for (int pos = pg; pos < F1 * K; pos += 16) {
        int f = pos / K, k = pos % K;
        float a0 = bias.x, a1 = bias.y, a2 = bias.z, a3 = bias.w;
        #pragma unroll
        for (int df = 0; df < 3; ++df) {
            int fi = 2 * f + df - 1;
            if (fi < 0 || fi >= F0) continue;
            #pragma unroll
            for (int dk = 0; dk < 3; ++dk) {
                int ki = k + dk - 1;
                if (ki < 0 || ki >= K) continue;
                float xv = xs[fi * K + ki];
                float sv = ssg[fi * K + ki];
                float4 wx = *(const float4*)&wsh2[(df * 3 + dk) * C1 + c4];
                float4 ws = *(const float4*)&wsh2[(9 + df * 3 + dk) * C1 + c4];
                a0 = fmaf(xv, wx.x, fmaf(sv, ws.x, a0));
                a1 = fmaf(xv, wx.y, fmaf(sv, ws.y, a1));
                a2 = fmaf(xv, wx.z, fmaf(sv, ws.z, a2));
                a3 = fmaf(xv, wx.w, fmaf(sv, ws.w, a3));
            }
        }
        ushort4 o;
        o.x = f2bf(fmaxf(a0, 0.f));
        o.y = f2bf(fmaxf(a1, 0.f));
        o.z = f2bf(fmaxf(a2, 0.f));
        o.w = f2bf(fmaxf(a3, 0.f));
        *(ushort4*)&h1[(((size_t)b * F1 + f) * K + k) * C1 + c4] = o;
    }
}

// ---- conv2 as MFMA GEMM, G=8 tile-staged: proven r2 structure with G
// doubled. r12's G=8 null was confounded (by-fi staging + dropped rotation;
// r13 proved by-fi alone is catastrophic). This keeps the PROVEN per-(g,df)
// tile staging + 2-deep bv rotation; only G doubles: grid (2,B) halves the
// weight L2 stream (1.2GB->600MB) and the per-block fixed costs' total.
// LDS 48KB -> 3 blocks/CU (same tier as conv3-fused: 170-reg target).
// Demand: 64 acc + av[4]16 + bA/bB 32 + ~40 addr ~= 152 <= 170.
template<int CIN, int COUT, int FIN, int G, int MINW>
__launch_bounds__(256, MINW)
__global__ void conv_mfma(const unsigned short* __restrict__ hin,
                          const unsigned short* __restrict__ wp,
                          const float* __restrict__ tb,
                          const unsigned short* __restrict__ zero16,
                          unsigned short* __restrict__ hout) {
    constexpr int CHW = CIN / 8;
    constexpr int LOGC = (CHW == 16) ? 4 : 3;
    constexpr int NT = COUT / 64;
    constexpr int CCS = CIN / 32;
    constexpr int NIT = 9 * CCS;
    __shared__ alignas(16) unsigned short lin[G * 3 * 16 * CIN];

    const int b = blockIdx.y;
    const int f2base = blockIdx.x * G;
    const int t = threadIdx.x;

    {
        constexpr int TOT = G * 3 * 16 * CHW;
        #pragma unroll 4
        for (int i = t; i < TOT; i += 256) {
            int c8 = i & (CHW - 1);
            int row = i >> LOGC;
            int p = row & 15;
            int tile = row >> 4;
            int df = tile % 3, g = tile / 3;
            int kin = p - 1;
            int fi = 2 * (f2base + g) + df - 1;
            bool valid = (kin >= 0) & (kin < K) & (fi >= 0);
            const unsigned short* src = valid
                ? hin + (((size_t)(b * FIN + fi)) * K + kin) * CIN + ((c8 ^ (p & 7)) << 3)
                : zero16;
            gl_lds16(src, &lin[i * 8]);
        }
    }
    __syncthreads();

    const int lane = t & 63;
    const int wave = t >> 6;
    const int m = lane & 15;
    const int quad = lane >> 4;
    const int nBase = wave * (COUT / 4);

    f32x4 acc[G][NT];
    #pragma unroll
    for (int nt = 0; nt < NT; ++nt) {
        float bias = tb[nBase + nt * 16 + m];
        #pragma unroll
        for (int g = 0; g < G; ++g)
            acc[g][nt] = f32x4{bias, bias, bias, bias};
    }

    auto loadA4 = [&](int it, int g0, bf16x8* av) {
        int df = it / (3 * CCS), dk = (it / CCS) % 3, cc = it % CCS;
        int p = m + dk; p = (p > 15) ? 15 : p;
        int cidx = (((cc * 4 + quad) ^ (p & 7)) << 3);
        #pragma unroll
        for (int g = 0; g < 4; ++g)
            av[g] = *(const bf16x8*)&lin[(((g0 + g) * 3 + df) * 16 + p) * CIN + cidx];
    };
    auto loadB = [&](int it, bf16x8* bv) {
        int df = it / (3 * CCS), dk = (it / CCS) % 3, cc = it % CCS;
        int chunk = (df * 3 + dk) * CCS + cc;
        #pragma unroll
        for (int nt = 0; nt < NT; ++nt)
            bv[nt] = *(const bf16x8*)(wp + (((chunk * COUT + nBase + nt * 16 + m)) << 5) + quad * 8);
    };
    auto mfma4 = [&](int g0, bf16x8* av, bf16x8* bv) {
        #pragma unroll
        for (int g = 0; g < 4; ++g)
            #pragma unroll
            for (int nt = 0; nt < NT; ++nt)
                acc[g0 + g][nt] = __builtin_amdgcn_mfma_f32_16x16x32_bf16(av[g], bv[nt], acc[g0 + g][nt], 0, 0, 0);
    };

    bf16x8 av[4], bA[NT], bB[NT];
    loadB(0, bA);
    #pragma unroll
    for (int it = 0; it < NIT; it += 2) {
        loadB(it + 1, bB);
        #pragma unroll
        for (int g0 = 0; g0 < G; g0 += 4) { loadA4(it, g0, av); mfma4(g0, av, bA); }
        if (it + 2 < NIT) loadB(it + 2, bA);
        #pragma unroll
        for (int g0 = 0; g0 < G; g0 += 4) { loadA4(it + 1, g0, av); mfma4(g0, av, bB); }
    }

    #pragma unroll
    for (int g = 0; g < G; ++g) {
        size_t rowbase = ((size_t)(b * (FIN / 2) + f2base + g)) * K;
        #pragma unroll
        for (int nt = 0; nt < NT; ++nt) {
            int col = nBase + nt * 16 + m;
            #pragma unroll
            for (int i = 0; i < 4; ++i) {
                int row = quad * 4 + i;
                if (row < K)
                    hout[(rowbase + row) * COUT + col] = f2bf(fmaxf(acc[g][nt][i], 0.f));
            }
        }
    }
}

// ---- conv3 + fused conv4 (round-11, VERBATIM — 170us, 84 VGPR, no spill) ----
template<int CIN, int COUT, int FIN, int MINW>
__launch_bounds__(256, MINW)
__global__ void conv_mfma_fused(const unsigned short* __restrict__ hin,
                                const unsigned short* __restrict__ wp,
                                const float* __restrict__ tb,
                                const unsigned short* __restrict__ zero16,
                                const float* __restrict__ w4,
                                float* __restrict__ pb) {
    constexpr int G = 4;
    constexpr int CHW = CIN / 8;
    constexpr int LOGC = (CHW == 16) ? 4 : 3;
    constexpr int NT = COUT / 64;
    constexpr int CCS = CIN / 32;
    constexpr int NIT = 9 * CCS;
    __shared__ alignas(16) unsigned short lin[G * 3 * 16 * CIN];
    __shared__ float red[4][4][4][2];        // [wave][quad][i][j]

    const int b = blockIdx.y;
    const int f2base = blockIdx.x * G;
    const int t = threadIdx.x;

    {
        constexpr int TOT = G * 3 * 16 * CHW;
        #pragma unroll
        for (int i = t; i < TOT; i += 256) {
            int c8 = i & (CHW - 1);
            int row = i >> LOGC;
            int p = row & 15;
            int tile = row >> 4;
            int df = tile % 3, g = tile / 3;
            int kin = p - 1;
            int fi = 2 * (f2base + g) + df - 1;
            bool valid = (kin >= 0) & (kin < K) & (fi >= 0);
            const unsigned short* src = valid
                ? hin + (((size_t)(b * FIN + fi)) * K + kin) * CIN + ((c8 ^ (p & 7)) << 3)
                : zero16;
            gl_lds16(src, &lin[i * 8]);
        }
    }
    __syncthreads();

    const int lane = t & 63;
    const int wave = t >> 6;
    const int m = lane & 15;
    const int quad = lane >> 4;
    const int nBase = wave * (COUT / 4);

    f32x4 acc[G][NT];
    #pragma unroll
    for (int nt = 0; nt < NT; ++nt) {
        float bias = tb[nBase + nt * 16 + m];
        #pragma unroll
        for (int g = 0; g < G; ++g)
            acc[g][nt] = f32x4{bias, bias, bias, bias};
    }

    auto loadA = [&](int it, bf16x8* av) {
        int df = it / (3 * CCS), dk = (it / CCS) % 3, cc = it % CCS;
        int p = m + dk; p = (p > 15) ? 15 : p;
        int cidx = (((cc * 4 + quad) ^ (p & 7)) << 3);
        #pragma unroll
        for (int g = 0; g < G; ++g)
            av[g] = *(const bf16x8*)&lin[((g * 3 + df) * 16 + p) * CIN + cidx];
    };
    auto loadB = [&](int it, bf16x8* bv) {
        int df = it / (3 * CCS), dk = (it / CCS) % 3, cc = it % CCS;
        int chunk = (df * 3 + dk) * CCS + cc;
        #pragma unroll
        for (int nt = 0; nt < NT; ++nt)
            bv[nt] = *(const bf16x8*)(wp + (((chunk * COUT + nBase + nt * 16 + m)) << 5) + quad * 8);
    };
    auto domfma = [&](bf16x8* av, bf16x8* bv) {
        #pragma unroll
        for (int g = 0; g < G; ++g)
            #pragma unroll
            for (int nt = 0; nt < NT; ++nt)
                acc[g][nt] = __builtin_amdgcn_mfma_f32_16x16x32_bf16(av[g], bv[nt], acc[g][nt], 0, 0, 0);
    };

    bf16x8 av[G], bA[NT], bB[NT];
    loadB(0, bA);
    #pragma unroll
    for (int it = 0; it < NIT; it += 2) {
        loadB(it + 1, bB);
        loadA(it, av);
        domfma(av, bA);
        if (it + 2 < NIT) loadB(it + 2, bA);
        loadA(it + 1, av);
        domfma(av, bB);
    }

    // ---- fused conv4 epilogue ----
    float part[4][2];
    #pragma unroll
    for (int i = 0; i < 4; ++i) { part[i][0] = 0.f; part[i][1] = 0.f; }
    #pragma unroll
    for (int g = 0; g < G; ++g) {
        int f = f2base + g;
        #pragma unroll
        for (int nt = 0; nt < NT; ++nt) {
            int c = nBase + nt * 16 + m;
            float w0 = w4[(0 * COUT + c) * F3 + f];
            float w1 = w4[(1 * COUT + c) * F3 + f];
            #pragma unroll
            for (int i = 0; i < 4; ++i) {
                float v = fmaxf(acc[g][nt][i], 0.f);
                part[i][0] = fmaf(v, w0, part[i][0]);
                part[i][1] = fmaf(v, w1, part[i][1]);
            }
        }
    }
    if (quad == 3) { part[2][0] = 0.f; part[2][1] = 0.f; part[3][0] = 0.f; part[3][1] = 0.f; }
    #pragma unroll
    for (int i = 0; i < 4; ++i)
        #pragma unroll
        for (int j = 0; j < 2; ++j) {
            float v = part[i][j];
            v += __shfl_xor(v, 1, 64);
            v += __shfl_xor(v, 2, 64);
            v += __shfl_xor(v, 4, 64);
            v += __shfl_xor(v, 8, 64);
            part[i][j] = v;
        }
    if (m == 0) {
        #pragma unroll
        for (int i = 0; i < 4; ++i) {
            red[wave][quad][i][0] = part[i][0];
            red[wave][quad][i][1] = part[i][1];
        }
    }
    __syncthreads();
    if (t < 2 * K) {
        int k = t >> 1, j = t & 1;
        float s = red[0][k >> 2][k & 3][j] + red[1][k >> 2][k & 3][j]
                + red[2][k >> 2][k & 3][j] + red[3][k >> 2][k & 3][j];
        pb[((size_t)b * 2 + blockIdx.x) * (2 * K) + t] = s;
    }
}

// ---- final: out[b,k,j] = pb[b][0][...] + pb[b][1][...] ----
__global__ void fin_kernel(const float* __restrict__ pb, float* __restrict__ out) {
    int idx = blockIdx.x * 256 + threadIdx.x;
    if (idx < B * 2 * K) {
        int b = idx / (2 * K), r = idx % (2 * K);
        out[idx] = pb[(size_t)b * (4 * K) + r] + pb[(size_t)b * (4 * K) + 2 * K + r];
    }
}

extern "C" void kernel_launch(void* const* d_in, const int* in_sizes, int n_in,
                              void* d_out, int out_size, void* d_ws, size_t ws_size,
                              hipStream_t stream) {
    const float* x   = (const float*)d_in[0];
    const float* sig = (const float*)d_in[1];
    const float* w1  = (const float*)d_in[2];
    const float* w2  = (const float*)d_in[3];
    const float* w3  = (const float*)d_in[4];
    const float* w4  = (const float*)d_in[5];
    const float* g1  = (const float*)d_in[6];
    const float* b1  = (const float*)d_in[7];
    const float* m1  = (const float*)d_in[8];
    const float* v1  = (const float*)d_in[9];
    const float* g2  = (const float*)d_in[10];
    const float* b2  = (const float*)d_in[11];
    const float* m2  = (const float*)d_in[12];
    const float* v2  = (const float*)d_in[13];
    const float* g3  = (const float*)d_in[14];
    const float* b3  = (const float*)d_in[15];
    const float* m3  = (const float*)d_in[16];
    const float* v3  = (const float*)d_in[17];

    char* ws = (char*)d_ws;
    size_t off = 0;
    auto alloc = [&](size_t bytes) {
        char* p = ws + off;
        off += (bytes + 255) & ~(size_t)255;
        return p;
    };
    unsigned short* h1  = (unsigned short*)alloc((size_t)B * F1 * K * C1 * 2);
    unsigned short* h2  = (unsigned short*)alloc((size_t)B * F2 * K * C2 * 2);
    float* w1f = (float*)alloc((size_t)C1 * 2 * 9 * 4);
    float* t1  = (float*)alloc((size_t)C1 * 4);
    unsigned short* wp2 = (unsigned short*)alloc((size_t)9 * C1 * C2 * 2);
    float* t2  = (float*)alloc((size_t)C2 * 4);
    unsigned short* wp3 = (unsigned short*)alloc((size_t)9 * C2 * C3 * 2);
    float* t3  = (float*)alloc((size_t)C3 * 4);
    float* zbuf = (float*)alloc(16);
    float* pb   = (float*)alloc((size_t)B * 2 * 2 * K * 4);   // per-block conv4 partials

    repack_w1<<<(C1 * 2 * 9 + 255) / 256, 256, 0, stream>>>(w1, g1, b1, m1, v1, w1f, t1, zbuf);
    repack_mfma<C1, C2><<<(9 * C1 * C2 + 255) / 256, 256, 0, stream>>>(w2, g2, b2, m2, v2, wp2, t2);
    repack_mfma<C2, C3><<<(9 * C2 * C3 + 255) / 256, 256, 0, stream>>>(w3, g3, b3, m3, v3, wp3, t3);

    conv1_kernel<<<B, 256, 0, stream>>>(x, sig, w1f, t1, h1);
    // conv2: G=8 tile-staged -> grid (2, B); LDS 48KB; weight stream halved
    conv_mfma<C1, C2, F1, 8, 2><<<dim3(F1 / 2 / 8, B), 256, 0, stream>>>(h1, wp2, t2, (const unsigned short*)zbuf, h2);
    // conv3 + fused conv4: grid (2, B); writes 28-float partials per block
    conv_mfma_fused<C2, C3, F2, 3><<<dim3(F2 / 2 / 4, B), 256, 0, stream>>>(h2, wp3, t3, (const unsigned short*)zbuf, w4, pb);
    fin_kernel<<<(B * 2 * K + 255) / 256, 256, 0, stream>>>(pb, (float*)d_out);
}

// Round 20
// 378.791 us; speedup vs baseline: 1.5245x; 1.0004x over previous
//
#include <hip/hip_runtime.h>
#include <hip/hip_bf16.h>

#define EPS_BN 1e-5f

constexpr int B  = 2048, F0 = 64, K = 14;
constexpr int C1 = 64,  F1 = 32;
constexpr int C2 = 128, F2 = 16;
constexpr int C3 = 256, F3 = 8;

typedef __attribute__((ext_vector_type(8))) short bf16x8;
typedef __attribute__((ext_vector_type(4))) float f32x4;

__device__ __forceinline__ float bf2f(unsigned short u) {
    union { unsigned int i; float f; } x; x.i = ((unsigned int)u) << 16; return x.f;
}
__device__ __forceinline__ unsigned short f2bf(float f) {
    union { float f; unsigned int i; } x; x.f = f;
    unsigned int r = (x.i + 0x7fffu + ((x.i >> 16) & 1u)) >> 16;
    return (unsigned short)r;
}

// async global->LDS 16B copy. HW: LDS dest = wave-uniform base + lane*16.
// Callers must keep whole waves active with per-lane-consecutive dests.
__device__ __forceinline__ void gl_lds16(const void* g, void* l) {
    __builtin_amdgcn_global_load_lds(
        (const __attribute__((address_space(1))) unsigned int*)g,
        (__attribute__((address_space(3))) unsigned int*)l,
        16, 0, 0);
}

// ---- fold BN into conv1 weights; also zero the 16B pad-source block ----
__global__ void repack_w1(const float* __restrict__ w1, const float* __restrict__ g,
                          const float* __restrict__ bb, const float* __restrict__ m,
                          const float* __restrict__ v, float* __restrict__ w1f,
                          float* __restrict__ t1, float* __restrict__ zbuf) {
    int i = blockIdx.x * 256 + threadIdx.x;
    if (i < 4) zbuf[i] = 0.0f;
    if (i < C1) {
        float s = g[i] * rsqrtf(v[i] + EPS_BN);
        t1[i] = bb[i] - m[i] * s;
    }
    if (i < C1 * 2 * 9) {
        int c = i / 18;
        float s = g[c] * rsqrtf(v[c] + EPS_BN);
        w1f[i] = w1[i] * s;
    }
}

// ---- repack conv weights into MFMA B-fragment layout, bf16, BN-folded ----
// wp[((chunk*COUT + n)*32) + kk] = W[tap][ci][n]*s[n], chunk=tap*(CIN/32)+cc, ci=cc*32+kk
template<int CIN, int COUT>
__global__ void repack_mfma(const float* __restrict__ w, const float* __restrict__ g,
                            const float* __restrict__ bb, const float* __restrict__ m,
                            const float* __restrict__ v, unsigned short* __restrict__ wp,
                            float* __restrict__ t) {
    int idx = blockIdx.x * 256 + threadIdx.x;
    if (idx < COUT) {
        float s = g[idx] * rsqrtf(v[idx] + EPS_BN);
        t[idx] = bb[idx] - m[idx] * s;
    }
    if (idx < 9 * CIN * COUT) {
        constexpr int CCS = CIN / 32;
        int kk = idx & 31;
        int rest = idx >> 5;
        int n = rest & (COUT - 1);
        int chunk = rest / COUT;
        int tap = chunk / CCS;
        int cc  = chunk & (CCS - 1);
        int ci = cc * 32 + kk;
        float s = g[n] * rsqrtf(v[n] + EPS_BN);
        wp[idx] = f2bf(w[(n * CIN + ci) * 9 + tap] * s);
    }
}

// ---- conv1 v2 (round-15, VERBATIM): 4 ch/thread, float4 weights, ushort4 st ----
__global__ void conv1_kernel(const float* __restrict__ x, const float* __restrict__ sig,
                             const float* __restrict__ w1f, const float* __restrict__ t1,
                             unsigned short* __restrict__ h1) {
    __shared__ float xs[F0 * K], ssg[F0 * K], wsh2[18 * C1], bsh[C1];
    int b = blockIdx.x, t = threadIdx.x;
    for (int i = t; i < F0 * K / 4; i += 256) {
        float4 xv = ((const float4*)(x + (size_t)b * F0 * K))[i];
        ((float4*)xs)[i] = xv;
        float4 sv = ((const float4*)(sig + (size_t)b * F0 * K))[i];
        sv.x *= 10.0f; sv.y *= 10.0f; sv.z *= 10.0f; sv.w *= 10.0f;
        ((float4*)ssg)[i] = sv;
    }
    for (int i = t; i < C1 * 18; i += 256) {
        int c = i / 18, r = i % 18;
        wsh2[r * C1 + c] = w1f[i];
    }
    if (t < C1) bsh[t] = t1[t];
    __syncthreads();
    const int c4 = (t & 15) * 4;
    const int pg = t >> 4;
    const float4 bias = *(const float4*)&bsh[c4];
    for (int pos = pg; pos < F1 * K; pos += 16) {
        int f = pos / K, k = pos % K;
        float a0 = bias.x, a1 = bias.y, a2 = bias.z, a3 = bias.w;
        #pragma unroll
        for (int df = 0; df < 3; ++df) {
            int fi = 2 * f + df - 1;
            if (fi < 0 || fi >= F0) continue;
            #pragma unroll
            for (int dk = 0; dk < 3; ++dk) {
                int ki = k + dk - 1;
                if (ki < 0 || ki >= K) continue;
                float xv = xs[fi * K + ki];
                float sv = ssg[fi * K + ki];
                float4 wx = *(const float4*)&wsh2[(df * 3 + dk) * C1 + c4];
                float4 ws = *(const float4*)&wsh2[(9 + df * 3 + dk) * C1 + c4];
                a0 = fmaf(xv, wx.x, fmaf(sv, ws.x, a0));
                a1 = fmaf(xv, wx.y, fmaf(sv, ws.y, a1));
                a2 = fmaf(xv, wx.z, fmaf(sv, ws.z, a2));
                a3 = fmaf(xv, wx.w, fmaf(sv, ws.w, a3));
            }
        }
        ushort4 o;
        o.x = f2bf(fmaxf(a0, 0.f));
        o.y = f2bf(fmaxf(a1, 0.f));
        o.z = f2bf(fmaxf(a2, 0.f));
        o.w = f2bf(fmaxf(a3, 0.f));
        *(ushort4*)&h1[(((size_t)b * F1 + f) * K + k) * C1 + c4] = o;
    }
}

// ---- conv2 as MFMA GEMM, G=8 tile-staged (round-19 structure, proven at
// 378.95us). ONLY change: MINW 2->3. LDS 48KB permits 3 blocks/CU; MINW=2's
// 256-reg budget likely left co-residency reg-capped at 2. MINW=3 caps at
// 170 total; demand ~152 (64 acc + ~88 arch, calibrated vs conv3-fused's
// 148 at same tier) -> fits, third block unlocks.
template<int CIN, int COUT, int FIN, int G, int MINW>
__launch_bounds__(256, MINW)
__global__ void conv_mfma(const unsigned short* __restrict__ hin,
                          const unsigned short* __restrict__ wp,
                          const float* __restrict__ tb,
                          const unsigned short* __restrict__ zero16,
                          unsigned short* __restrict__ hout) {
    constexpr int CHW = CIN / 8;
    constexpr int LOGC = (CHW == 16) ? 4 : 3;
    constexpr int NT = COUT / 64;
    constexpr int CCS = CIN / 32;
    constexpr int NIT = 9 * CCS;
    __shared__ alignas(16) unsigned short lin[G * 3 * 16 * CIN];

    const int b = blockIdx.y;
    const int f2base = blockIdx.x * G;
    const int t = threadIdx.x;

    {
        constexpr int TOT = G * 3 * 16 * CHW;
        #pragma unroll 4
        for (int i = t; i < TOT; i += 256) {
            int c8 = i & (CHW - 1);
            int row = i >> LOGC;
            int p = row & 15;
            int tile = row >> 4;
            int df = tile % 3, g = tile / 3;
            int kin = p - 1;
            int fi = 2 * (f2base + g) + df - 1;
            bool valid = (kin >= 0) & (kin < K) & (fi >= 0);
            const unsigned short* src = valid
                ? hin + (((size_t)(b * FIN + fi)) * K + kin) * CIN + ((c8 ^ (p & 7)) << 3)
                : zero16;
            gl_lds16(src, &lin[i * 8]);
        }
    }
    __syncthreads();

    const int lane = t & 63;
    const int wave = t >> 6;
    const int m = lane & 15;
    const int quad = lane >> 4;
    const int nBase = wave * (COUT / 4);

    f32x4 acc[G][NT];
    #pragma unroll
    for (int nt = 0; nt < NT; ++nt) {
        float bias = tb[nBase + nt * 16 + m];
        #pragma unroll
        for (int g = 0; g < G; ++g)
            acc[g][nt] = f32x4{bias, bias, bias, bias};
    }

    auto loadA4 = [&](int it, int g0, bf16x8* av) {
        int df = it / (3 * CCS), dk = (it / CCS) % 3, cc = it % CCS;
        int p = m + dk; p = (p > 15) ? 15 : p;
        int cidx = (((cc * 4 + quad) ^ (p & 7)) << 3);
        #pragma unroll
        for (int g = 0; g < 4; ++g)
            av[g] = *(const bf16x8*)&lin[(((g0 + g) * 3 + df) * 16 + p) * CIN + cidx];
    };
    auto loadB = [&](int it, bf16x8* bv) {
        int df = it / (3 * CCS), dk = (it / CCS) % 3, cc = it % CCS;
        int chunk = (df * 3 + dk) * CCS + cc;
        #pragma unroll
        for (int nt = 0; nt < NT; ++nt)
            bv[nt] = *(const bf16x8*)(wp + (((chunk * COUT + nBase + nt * 16 + m)) << 5) + quad * 8);
    };
    auto mfma4 = [&](int g0, bf16x8* av, bf16x8* bv) {
        #pragma unroll
        for (int g = 0; g < 4; ++g)
            #pragma unroll
            for (int nt = 0; nt < NT; ++nt)
                acc[g0 + g][nt] = __builtin_amdgcn_mfma_f32_16x16x32_bf16(av[g], bv[nt], acc[g0 + g][nt], 0, 0, 0);
    };

    bf16x8 av[4], bA[NT], bB[NT];
    loadB(0, bA);
    #pragma unroll
    for (int it = 0; it < NIT; it += 2) {
        loadB(it + 1, bB);
        #pragma unroll
        for (int g0 = 0; g0 < G; g0 += 4) { loadA4(it, g0, av); mfma4(g0, av, bA); }
        if (it + 2 < NIT) loadB(it + 2, bA);
        #pragma unroll
        for (int g0 = 0; g0 < G; g0 += 4) { loadA4(it + 1, g0, av); mfma4(g0, av, bB); }
    }

    #pragma unroll
    for (int g = 0; g < G; ++g) {
        size_t rowbase = ((size_t)(b * (FIN / 2) + f2base + g)) * K;
        #pragma unroll
        for (int nt = 0; nt < NT; ++nt) {
            int col = nBase + nt * 16 + m;
            #pragma unroll
            for (int i = 0; i < 4; ++i) {
                int row = quad * 4 + i;
                if (row < K)
                    hout[(rowbase + row) * COUT + col] = f2bf(fmaxf(acc[g][nt][i], 0.f));
            }
        }
    }
}

// ---- conv3 + fused conv4 (round-11, VERBATIM — 169us, 84 VGPR, no spill) ----
template<int CIN, int COUT, int FIN, int MINW>
__launch_bounds__(256, MINW)
__global__ void conv_mfma_fused(const unsigned short* __restrict__ hin,
                                const unsigned short* __restrict__ wp,
                                const float* __restrict__ tb,
                                const unsigned short* __restrict__ zero16,
                                const float* __restrict__ w4,
                                float* __restrict__ pb) {
    constexpr int G = 4;
    constexpr int CHW = CIN / 8;
    constexpr int LOGC = (CHW == 16) ? 4 : 3;
    constexpr int NT = COUT / 64;
    constexpr int CCS = CIN / 32;
    constexpr int NIT = 9 * CCS;
    __shared__ alignas(16) unsigned short lin[G * 3 * 16 * CIN];
    __shared__ float red[4][4][4][2];        // [wave][quad][i][j]

    const int b = blockIdx.y;
    const int f2base = blockIdx.x * G;
    const int t = threadIdx.x;

    {
        constexpr int TOT = G * 3 * 16 * CHW;
        #pragma unroll
        for (int i = t; i < TOT; i += 256) {
            int c8 = i & (CHW - 1);
            int row = i >> LOGC;
            int p = row & 15;
            int tile = row >> 4;
            int df = tile % 3, g = tile / 3;
            int kin = p - 1;
            int fi = 2 * (f2base + g) + df - 1;
            bool valid = (kin >= 0) & (kin < K) & (fi >= 0);
            const unsigned short* src = valid
                ? hin + (((size_t)(b * FIN + fi)) * K + kin) * CIN + ((c8 ^ (p & 7)) << 3)
                : zero16;
            gl_lds16(src, &lin[i * 8]);
        }
    }
    __syncthreads();

    const int lane = t & 63;
    const int wave = t >> 6;
    const int m = lane & 15;
    const int quad = lane >> 4;
    const int nBase = wave * (COUT / 4);

    f32x4 acc[G][NT];
    #pragma unroll
    for (int nt = 0; nt < NT; ++nt) {
        float bias = tb[nBase + nt * 16 + m];
        #pragma unroll
        for (int g = 0; g < G; ++g)
            acc[g][nt] = f32x4{bias, bias, bias, bias};
    }

    auto loadA = [&](int it, bf16x8* av) {
        int df = it / (3 * CCS), dk = (it / CCS) % 3, cc = it % CCS;
        int p = m + dk; p = (p > 15) ? 15 : p;
        int cidx = (((cc * 4 + quad) ^ (p & 7)) << 3);
        #pragma unroll
        for (int g = 0; g < G; ++g)
            av[g] = *(const bf16x8*)&lin[((g * 3 + df) * 16 + p) * CIN + cidx];
    };
    auto loadB = [&](int it, bf16x8* bv) {
        int df = it / (3 * CCS), dk = (it / CCS) % 3, cc = it % CCS;
        int chunk = (df * 3 + dk) * CCS + cc;
        #pragma unroll
        for (int nt = 0; nt < NT; ++nt)
            bv[nt] = *(const bf16x8*)(wp + (((chunk * COUT + nBase + nt * 16 + m)) << 5) + quad * 8);
    };
    auto domfma = [&](bf16x8* av, bf16x8* bv) {
        #pragma unroll
        for (int g = 0; g < G; ++g)
            #pragma unroll
            for (int nt = 0; nt < NT; ++nt)
                acc[g][nt] = __builtin_amdgcn_mfma_f32_16x16x32_bf16(av[g], bv[nt], acc[g][nt], 0, 0, 0);
    };

    bf16x8 av[G], bA[NT], bB[NT];
    loadB(0, bA);
    #pragma unroll
    for (int it = 0; it < NIT; it += 2) {
        loadB(it + 1, bB);
        loadA(it, av);
        domfma(av, bA);
        if (it + 2 < NIT) loadB(it + 2, bA);
        loadA(it + 1, av);
        domfma(av, bB);
    }

    // ---- fused conv4 epilogue ----
    float part[4][2];
    #pragma unroll
    for (int i = 0; i < 4; ++i) { part[i][0] = 0.f; part[i][1] = 0.f; }
    #pragma unroll
    for (int g = 0; g < G; ++g) {
        int f = f2base + g;
        #pragma unroll
        for (int nt = 0; nt < NT; ++nt) {
            int c = nBase + nt * 16 + m;
            float w0 = w4[(0 * COUT + c) * F3 + f];
            float w1 = w4[(1 * COUT + c) * F3 + f];
            #pragma unroll
            for (int i = 0; i < 4; ++i) {
                float v = fmaxf(acc[g][nt][i], 0.f);
                part[i][0] = fmaf(v, w0, part[i][0]);
                part[i][1] = fmaf(v, w1, part[i][1]);
            }
        }
    }
    if (quad == 3) { part[2][0] = 0.f; part[2][1] = 0.f; part[3][0] = 0.f; part[3][1] = 0.f; }
    #pragma unroll
    for (int i = 0; i < 4; ++i)
        #pragma unroll
        for (int j = 0; j < 2; ++j) {
            float v = part[i][j];
            v += __shfl_xor(v, 1, 64);
            v += __shfl_xor(v, 2, 64);
            v += __shfl_xor(v, 4, 64);
            v += __shfl_xor(v, 8, 64);
            part[i][j] = v;
        }
    if (m == 0) {
        #pragma unroll
        for (int i = 0; i < 4; ++i) {
            red[wave][quad][i][0] = part[i][0];
            red[wave][quad][i][1] = part[i][1];
        }
    }
    __syncthreads();
    if (t < 2 * K) {
        int k = t >> 1, j = t & 1;
        float s = red[0][k >> 2][k & 3][j] + red[1][k >> 2][k & 3][j]
                + red[2][k >> 2][k & 3][j] + red[3][k >> 2][k & 3][j];
        pb[((size_t)b * 2 + blockIdx.x) * (2 * K) + t] = s;
    }
}

// ---- final: out[b,k,j] = pb[b][0][...] + pb[b][1][...] ----
__global__ void fin_kernel(const float* __restrict__ pb, float* __restrict__ out) {
    int idx = blockIdx.x * 256 + threadIdx.x;
    if (idx < B * 2 * K) {
        int b = idx / (2 * K), r = idx % (2 * K);
        out[idx] = pb[(size_t)b * (4 * K) + r] + pb[(size_t)b * (4 * K) + 2 * K + r];
    }
}

extern "C" void kernel_launch(void* const* d_in, const int* in_sizes, int n_in,
                              void* d_out, int out_size, void* d_ws, size_t ws_size,
                              hipStream_t stream) {
    const float* x   = (const float*)d_in[0];
    const float* sig = (const float*)d_in[1];
    const float* w1  = (const float*)d_in[2];
    const float* w2  = (const float*)d_in[3];
    const float* w3  = (const float*)d_in[4];
    const float* w4  = (const float*)d_in[5];
    const float* g1  = (const float*)d_in[6];
    const float* b1  = (const float*)d_in[7];
    const float* m1  = (const float*)d_in[8];
    const float* v1  = (const float*)d_in[9];
    const float* g2  = (const float*)d_in[10];
    const float* b2  = (const float*)d_in[11];
    const float* m2  = (const float*)d_in[12];
    const float* v2  = (const float*)d_in[13];
    const float* g3  = (const float*)d_in[14];
    const float* b3  = (const float*)d_in[15];
    const float* m3  = (const float*)d_in[16];
    const float* v3  = (const float*)d_in[17];

    char* ws = (char*)d_ws;
    size_t off = 0;
    auto alloc = [&](size_t bytes) {
        char* p = ws + off;
        off += (bytes + 255) & ~(size_t)255;
        return p;
    };
    unsigned short* h1  = (unsigned short*)alloc((size_t)B * F1 * K * C1 * 2);
    unsigned short* h2  = (unsigned short*)alloc((size_t)B * F2 * K * C2 * 2);
    float* w1f = (float*)alloc((size_t)C1 * 2 * 9 * 4);
    float* t1  = (float*)alloc((size_t)C1 * 4);
    unsigned short* wp2 = (unsigned short*)alloc((size_t)9 * C1 * C2 * 2);
    float* t2  = (float*)alloc((size_t)C2 * 4);
    unsigned short* wp3 = (unsigned short*)alloc((size_t)9 * C2 * C3 * 2);
    float* t3  = (float*)alloc((size_t)C3 * 4);
    float* zbuf = (float*)alloc(16);
    float* pb   = (float*)alloc((size_t)B * 2 * 2 * K * 4);   // per-block conv4 partials

    repack_w1<<<(C1 * 2 * 9 + 255) / 256, 256, 0, stream>>>(w1, g1, b1, m1, v1, w1f, t1, zbuf);
    repack_mfma<C1, C2><<<(9 * C1 * C2 + 255) / 256, 256, 0, stream>>>(w2, g2, b2, m2, v2, wp2, t2);
    repack_mfma<C2, C3><<<(9 * C2 * C3 + 255) / 256, 256, 0, stream>>>(w3, g3, b3, m3, v3, wp3, t3);

    conv1_kernel<<<B, 256, 0, stream>>>(x, sig, w1f, t1, h1);
    // conv2: G=8 tile-staged -> grid (2, B); LDS 48KB; MINW=3 (3 blocks/CU)
    conv_mfma<C1, C2, F1, 8, 3><<<dim3(F1 / 2 / 8, B), 256, 0, stream>>>(h1, wp2, t2, (const unsigned short*)zbuf, h2);
    // conv3 + fused conv4: grid (2, B); writes 28-float partials per block
    conv_mfma_fused<C2, C3, F2, 3><<<dim3(F2 / 2 / 4, B), 256, 0, stream>>>(h2, wp3, t3, (const unsigned short*)zbuf, w4, pb);
    fin_kernel<<<(B * 2 * K + 255) / 256, 256, 0, stream>>>(pb, (float*)d_out);
}